// Round 6
// baseline (57.456 us; speedup 1.0000x reference)
//
#include <hip/hip_runtime.h>
#include <hip/hip_bf16.h>

#define B_DIM 128
#define C_DIM 128
#define T_DIM 777
#define T_PAD 832   // 52 * 16
#define NS    52    // 16-t steps per b
#define STEPS 13    // steps per th chunk (4 chunks)
#define P_DIM 500
#define P_PAD 512
#define NCLS  5
#define EPSV  1e-4f

typedef unsigned short u16;
typedef unsigned int   u32;
typedef __attribute__((ext_vector_type(8))) short short8;   // 8 bf16 = 4 VGPR
typedef __attribute__((ext_vector_type(4))) float f32x4;

__device__ __forceinline__ u16 f2bf(float f) {
    u32 u = __float_as_uint(f);
    u += 0x7FFFu + ((u >> 16) & 1u);     // RNE
    return (u16)(u >> 16);
}

__device__ __forceinline__ u32 cvt_pk_bf16(float a, float b) {
    u32 r;
    asm("v_cvt_pk_bf16_f32 %0, %1, %2" : "=v"(r) : "v"(a), "v"(b));
    return r;
}

// ---------------- kernel 1: x fp32 -> fragment-major bf16 granules + x2 ----------------
// Output granule G = ((b*52 + s)*4 + k)*64 + l  holds x[b][c = k*32+(l>>4)*8 .. +8][t = s*16+(l&15)]
// so the GEMM's B-frag load for (s,k) is ONE coalesced dwordx4 per wave.
__global__ __launch_bounds__(256) void prep_x(const float* __restrict__ x,
                                              int4* __restrict__ xg,
                                              float* __restrict__ x2) {
    const int tc = blockIdx.x;           // 0..12 (64 t's each; covers t<832)
    const int b  = blockIdx.y;
    const int tid = threadIdx.x, w = tid >> 6, l = tid & 63;
    __shared__ __align__(16) u16 xt[64][136];  // +8 u16 pad (272B row, 16B-aligned)
    const int t_loc = w * 16 + (l & 15);
    const int cg = l >> 4;                     // 0..3
    const int t = tc * 64 + t_loc;
    const float* xb = x + (size_t)b * C_DIM * T_DIM;
    float acc = 0.f;
#pragma unroll 8
    for (int c0 = 0; c0 < C_DIM; c0 += 4) {
        int c = c0 + cg;
        float v = (t < T_DIM) ? xb[c * T_DIM + t] : 0.f;
        acc = fmaf(v, v, acc);
        xt[t_loc][c] = f2bf(v);
    }
    acc += __shfl_xor(acc, 16);
    acc += __shfl_xor(acc, 32);
    if (cg == 0) x2[b * T_PAD + t] = (t < T_DIM) ? acc : 1e30f;   // padded t never wins
    __syncthreads();
    int4* dst = xg + ((size_t)b * 13 + tc) * 1024;
#pragma unroll
    for (int q = 0; q < 4; ++q) {
        const int f  = q * 256 + tid;                    // 1024 granules per block
        const int tl = ((f >> 8) << 4) + (f & 15);       // ss*16 + (f&15)
        const int cb = (((f >> 6) & 3) << 6) + (((f >> 4) & 3) << 4);  // kk*64 + kq*16 bytes
        dst[f] = *(const int4*)((const char*)xt + tl * 272 + cb);
    }
}

// ---------------- kernel 2: barrier-free direct-load MFMA GEMM + min over t ----------------
// grid 1024 = b(128) x pt(2) x th(4); block 256 (4 waves, all same b/th -> L1 B-frag reuse);
// wave owns 64 protos (A-frags in regs). No LDS, no __syncthreads.
// wsmin[th][b][p] = min over th's 208 t's of (x2[t] - 2*x.p)
__global__ __launch_bounds__(256, 3) void gemm_min(
    const int4* __restrict__ xg,
    const float* __restrict__ x2,
    const float* __restrict__ proto,
    float* __restrict__ wsmin) {

    const int o   = blockIdx.x;               // XCD-bijective: 1024 = 8 XCD x 128
    const int xcd = o & 7, j = o >> 3;        // j: 0..127
    const int b   = xcd * 16 + (j >> 3);
    const int r   = j & 7;
    const int pt  = r >> 2, th = r & 3;

    const int tid = threadIdx.x;
    const int w = tid >> 6, l = tid & 63;
    const int row16 = l & 15, kq = l >> 4;    // kq: 0..3
    const int wp = pt * 256 + w * 64;         // wave's proto base (64 rows)

    // ---- prototype A-frags in registers (bf16 via cvt_pk) ----
    short8 afr[4][4];
#pragma unroll
    for (int ps = 0; ps < 4; ++ps) {
        const int rr = wp + ps * 16 + row16;
#pragma unroll
        for (int k = 0; k < 4; ++k) {
            const int k0 = k * 32 + kq * 8;
            union { short8 s; u32 d[4]; } t;
            if (rr < P_DIM) {
                float4 u0 = *(const float4*)(proto + rr * C_DIM + k0);
                float4 u1 = *(const float4*)(proto + rr * C_DIM + k0 + 4);
                t.d[0] = cvt_pk_bf16(u0.x, u0.y);
                t.d[1] = cvt_pk_bf16(u0.z, u0.w);
                t.d[2] = cvt_pk_bf16(u1.x, u1.y);
                t.d[3] = cvt_pk_bf16(u1.z, u1.w);
            } else {
                t.d[0] = t.d[1] = t.d[2] = t.d[3] = 0u;
            }
            afr[ps][k] = t.s;
        }
    }

    const int4*  gb = xg + ((size_t)b * NS + th * STEPS) * 256;   // 256 granules per s-step
    const float* xw = x2 + (size_t)b * T_PAD + th * (STEPS * 16);

    f32x4 minv[4];
#pragma unroll
    for (int ps = 0; ps < 4; ++ps) minv[ps] = (f32x4){1e30f, 1e30f, 1e30f, 1e30f};

    short8 bA[4], bB[4];
    float  xA, xB;

    auto LOAD = [&](short8 (&bf)[4], float& xv, int s) {
#pragma unroll
        for (int k = 0; k < 4; ++k)
            bf[k] = *(const short8*)(gb + s * 256 + k * 64 + l);   // coalesced 1KB/wave
        xv = xw[s * 16 + row16];
    };
    auto STEP = [&](short8 (&bf)[4], float xv) {
        f32x4 acc[4];
#pragma unroll
        for (int ps = 0; ps < 4; ++ps) acc[ps] = (f32x4){0.f, 0.f, 0.f, 0.f};
        __builtin_amdgcn_s_setprio(1);
#pragma unroll
        for (int k = 0; k < 4; ++k)
#pragma unroll
            for (int ps = 0; ps < 4; ++ps)
                acc[ps] = __builtin_amdgcn_mfma_f32_16x16x32_bf16(
                    afr[ps][k], bf[k], acc[ps], 0, 0, 0);
        __builtin_amdgcn_s_setprio(0);
#pragma unroll
        for (int ps = 0; ps < 4; ++ps)
#pragma unroll
            for (int q = 0; q < 4; ++q)
                minv[ps][q] = fminf(minv[ps][q], fmaf(-2.f, acc[ps][q], xv));
    };

    LOAD(bA, xA, 0);
    for (int s2 = 0; s2 < 6; ++s2) {          // covers s = 0..11, 2 steps/iter
        LOAD(bB, xB, 2 * s2 + 1);
        STEP(bA, xA);
        LOAD(bA, xA, 2 * s2 + 2);
        STEP(bB, xB);
    }
    STEP(bA, xA);                              // s = 12

    // min across the 16 t-columns (lane bits 0..3)
#pragma unroll
    for (int m = 1; m <= 8; m <<= 1)
#pragma unroll
        for (int ps = 0; ps < 4; ++ps)
#pragma unroll
            for (int q = 0; q < 4; ++q)
                minv[ps][q] = fminf(minv[ps][q], __shfl_xor(minv[ps][q], m));

    if (row16 == 0) {
#pragma unroll
        for (int ps = 0; ps < 4; ++ps) {
            const int p = wp + ps * 16 + kq * 4;   // C/D: row = kq*4+q
            *(float4*)(&wsmin[((size_t)th * B_DIM + b) * P_PAD + p]) =
                make_float4(minv[ps][0], minv[ps][1], minv[ps][2], minv[ps][3]);
        }
    }
}

// ---------------- kernel 3: p2 + 4-way min-merge + clamp + log-sim + @W ----------------
__global__ __launch_bounds__(256) void combine_logits(
    const float* __restrict__ proto, const float* __restrict__ lw,
    const float* __restrict__ wsmin, float* __restrict__ out) {
    const int b = blockIdx.x, tid = threadIdx.x;
    float a[NCLS] = {0.f, 0.f, 0.f, 0.f, 0.f};
    for (int p = tid; p < P_DIM; p += 256) {
        const float4* pr = (const float4*)(proto + p * C_DIM);
        float p2 = 0.f;
#pragma unroll
        for (int i = 0; i < 32; ++i) {
            float4 u = pr[i];
            p2 += u.x*u.x + u.y*u.y + u.z*u.z + u.w*u.w;
        }
        const float m0 = wsmin[((size_t)0 * B_DIM + b) * P_PAD + p];
        const float m1 = wsmin[((size_t)1 * B_DIM + b) * P_PAD + p];
        const float m2 = wsmin[((size_t)2 * B_DIM + b) * P_PAD + p];
        const float m3 = wsmin[((size_t)3 * B_DIM + b) * P_PAD + p];
        const float m  = fminf(fminf(m0, m1), fminf(m2, m3));
        const float md = fmaxf(m + p2, 0.f);
        const float sim = logf((md + 1.f) / (md + EPSV));
#pragma unroll
        for (int n = 0; n < NCLS; ++n) a[n] = fmaf(sim, lw[p * NCLS + n], a[n]);
    }
#pragma unroll
    for (int m = 1; m <= 32; m <<= 1)
#pragma unroll
        for (int n = 0; n < NCLS; ++n) a[n] += __shfl_xor(a[n], m);
    __shared__ float red[4][NCLS];
    const int w = tid >> 6, l = tid & 63;
    if (l == 0) {
#pragma unroll
        for (int n = 0; n < NCLS; ++n) red[w][n] = a[n];
    }
    __syncthreads();
    if (tid < NCLS)
        out[b * NCLS + tid] = red[0][tid] + red[1][tid] + red[2][tid] + red[3][tid];
}

// ---------------- fallback (no workspace): slow but correct ----------------
__global__ __launch_bounds__(256) void fallback_k(const float* __restrict__ x,
                                                  const float* __restrict__ proto,
                                                  const float* __restrict__ lw,
                                                  float* __restrict__ out) {
    __shared__ float x2s[T_DIM];
    __shared__ float sims[P_DIM];
    int b = blockIdx.x, tid = threadIdx.x;
    for (int t = tid; t < T_DIM; t += 256) {
        float a = 0.f;
        for (int c = 0; c < C_DIM; ++c) { float v = x[((size_t)b * C_DIM + c) * T_DIM + t]; a = fmaf(v, v, a); }
        x2s[t] = a;
    }
    __syncthreads();
    for (int p = tid; p < P_DIM; p += 256) {
        float p2 = 0.f;
        for (int c = 0; c < C_DIM; ++c) { float v = proto[p * C_DIM + c]; p2 = fmaf(v, v, p2); }
        float mind = 1e30f;
        for (int t = 0; t < T_DIM; ++t) {
            float xp = 0.f;
            for (int c = 0; c < C_DIM; ++c)
                xp = fmaf(x[((size_t)b * C_DIM + c) * T_DIM + t], proto[p * C_DIM + c], xp);
            float d = fmaxf(x2s[t] - 2.f * xp + p2, 0.f);
            mind = fminf(mind, d);
        }
        sims[p] = logf((mind + 1.f) / (mind + EPSV));
    }
    __syncthreads();
    if (tid < NCLS) {
        float a = 0.f;
        for (int p = 0; p < P_DIM; ++p) a = fmaf(sims[p], lw[p * NCLS + tid], a);
        out[b * NCLS + tid] = a;
    }
}

extern "C" void kernel_launch(void* const* d_in, const int* in_sizes, int n_in,
                              void* d_out, int out_size, void* d_ws, size_t ws_size,
                              hipStream_t stream) {
    const float* x     = (const float*)d_in[0];
    const float* proto = (const float*)d_in[1];
    const float* lw    = (const float*)d_in[2];
    float* out = (float*)d_out;

    const size_t xg_bytes = (size_t)B_DIM * NS * 4 * 64 * 16;        // 27,262,976
    const size_t x2_off   = xg_bytes;
    const size_t min_off  = x2_off + (size_t)B_DIM * T_PAD * 4;
    const size_t need     = min_off + (size_t)4 * B_DIM * P_PAD * 4; // ~28.7 MB

    if (ws_size >= need) {
        int4*  xg    = (int4*)d_ws;
        float* x2    = (float*)((char*)d_ws + x2_off);
        float* wsmin = (float*)((char*)d_ws + min_off);
        prep_x        <<<dim3(13, B_DIM), 256, 0, stream>>>(x, xg, x2);
        gemm_min      <<<dim3(1024),      256, 0, stream>>>(xg, x2, proto, wsmin);
        combine_logits<<<dim3(B_DIM),     256, 0, stream>>>(proto, lw, wsmin, out);
    } else {
        fallback_k<<<dim3(B_DIM), 256, 0, stream>>>(x, proto, lw, out);
    }
}

// Round 7
// 43.627 us; speedup vs baseline: 1.3170x; 1.3170x over previous
//
#include <hip/hip_runtime.h>
#include <hip/hip_bf16.h>

#define B_DIM 128
#define C_DIM 128
#define T_DIM 777
#define P_DIM 500
#define P_PAD 512
#define NCLS  5
#define EPSV  1e-4f
#define NTILE 13      // 64-t tiles
#define SPL   7       // th0: tiles 0..6, th1: tiles 7..12

typedef unsigned short u16;
typedef unsigned int   u32;
typedef __attribute__((ext_vector_type(8))) short short8;   // 8 bf16 = 4 VGPR
typedef __attribute__((ext_vector_type(4))) float f32x4;
typedef float float4u __attribute__((ext_vector_type(4), aligned(4)));  // stride 777 odd -> 4B align

__device__ __forceinline__ u32 cvt_pk_bf16(float a, float b) {
    u32 r;
    asm("v_cvt_pk_bf16_f32 %0, %1, %2" : "=v"(r) : "v"(a), "v"(b));
    return r;
}

// ---------------- fused: one block covers ALL 512 protos -> x read ONCE ----------------
// grid 256 = b(128) x th(2), 1 block/CU; block 512 thr (8 waves); wave owns 64 protos in regs.
// Per 64-t tile: coalesced fp32 loads (1 tile ahead) -> cvt_pk -> swizzled LDS -> 64 MFMA/wave
// -> fold min(x2 - 2 x.p). wsmin[th][b][p]; p2/clamp/log deferred to combine.
__global__ __launch_bounds__(512, 2) void fused_gemm_min(
    const float* __restrict__ x,
    const float* __restrict__ proto,
    float* __restrict__ wsmin) {

    const int o   = blockIdx.x;               // XCD-bijective: 256 = 8 XCD x 32
    const int xcd = o & 7, j = o >> 3;        // j: 0..31
    const int b   = xcd * 16 + (j >> 1);
    const int th  = j & 1;
    const int it0 = th ? SPL : 0;
    const int itN = th ? NTILE : SPL;

    const int tid = threadIdx.x;
    const int w = tid >> 6, l = tid & 63;
    const int row16 = l & 15, kq = l >> 4;    // kq: 0..3
    const int wp = w * 64;                    // wave's proto base (8 waves x 64 = 512)

    // loader: thread owns 4 c-rows x 4 t-cols; block covers 128c x 64t
    const int c0  = (tid >> 4) << 2;          // 0..124
    const int tl0 = (tid & 15) << 2;          // 0..60

    __shared__ __align__(16) char  smem[64 * 256];   // 64 t-rows x 128 c bf16, 16B-granule XOR swizzle
    __shared__ __align__(16) float x2p[8][64];       // per-wave x2 partials
    __shared__ __align__(16) float x2f[64];          // finalized x2 for current tile

    const float* xb = x + (size_t)b * C_DIM * T_DIM;

    float vb[4][4];   // [c-row][t-col], compile-time indexed (rule #20)
    auto loadv = [&](int it) {
        const int tb = it * 64 + tl0;
        if (tb + 3 < T_DIM) {
#pragma unroll
            for (int r = 0; r < 4; ++r) {
                float4u u = *(const float4u*)(xb + (c0 + r) * T_DIM + tb);
                vb[r][0]=u[0]; vb[r][1]=u[1]; vb[r][2]=u[2]; vb[r][3]=u[3];
            }
        } else {
#pragma unroll
            for (int r = 0; r < 4; ++r)
#pragma unroll
                for (int jj = 0; jj < 4; ++jj) {
                    const int t = (tb + jj < T_DIM) ? (tb + jj) : (T_DIM - 1);  // clamp; x2f kills pad
                    vb[r][jj] = xb[(c0 + r) * T_DIM + t];
                }
        }
    };

    // convert + transposed swizzled LDS write + x2 partials (in-wave c-reduce, 8 shfl)
    auto write_tile = [&]() {
        float s[4];
#pragma unroll
        for (int jj = 0; jj < 4; ++jj)
            s[jj] = vb[0][jj]*vb[0][jj] + vb[1][jj]*vb[1][jj]
                  + vb[2][jj]*vb[2][jj] + vb[3][jj]*vb[3][jj];
#pragma unroll
        for (int jj = 0; jj < 4; ++jj) {
            const u32 lo = cvt_pk_bf16(vb[0][jj], vb[1][jj]);
            const u32 hi = cvt_pk_bf16(vb[2][jj], vb[3][jj]);
            const int tl  = tl0 + jj;
            const int off = tl * 256 + (((c0 >> 3) ^ (tl & 7)) << 4) + ((c0 & 4) << 1);
            *(uint2*)(smem + off) = make_uint2(lo, hi);
        }
        // reduce over the wave's 16 c's (lane bits 4..5)
#pragma unroll
        for (int m = 16; m <= 32; m <<= 1)
#pragma unroll
            for (int jj = 0; jj < 4; ++jj) s[jj] += __shfl_xor(s[jj], m);
        if (l < 16)                                    // tl0 == l*4 for these lanes
            *(float4*)(&x2p[w][tl0]) = make_float4(s[0], s[1], s[2], s[3]);
    };

    // ---- prologue: issue first tile's loads, then load protos (latency overlaps) ----
    loadv(it0);

    short8 afr[4][4];
#pragma unroll
    for (int ps = 0; ps < 4; ++ps) {
        const int rr = wp + ps * 16 + row16;
#pragma unroll
        for (int k = 0; k < 4; ++k) {
            const int k0 = k * 32 + kq * 8;
            union { short8 s; u32 d[4]; } t;
            if (rr < P_DIM) {
                float4 u0 = *(const float4*)(proto + rr * C_DIM + k0);
                float4 u1 = *(const float4*)(proto + rr * C_DIM + k0 + 4);
                t.d[0] = cvt_pk_bf16(u0.x, u0.y);
                t.d[1] = cvt_pk_bf16(u0.z, u0.w);
                t.d[2] = cvt_pk_bf16(u1.x, u1.y);
                t.d[3] = cvt_pk_bf16(u1.z, u1.w);
            } else {
                t.d[0] = t.d[1] = t.d[2] = t.d[3] = 0u;
            }
            afr[ps][k] = t.s;
        }
    }

    f32x4 minv[4];
#pragma unroll
    for (int ps = 0; ps < 4; ++ps) minv[ps] = (f32x4){1e30f, 1e30f, 1e30f, 1e30f};

    write_tile();
    __syncthreads();                           // bar A: tile it0 + partials ready

    for (int it = it0; it < itN; ++it) {
        const bool more = (it + 1 < itN);
        if (more) loadv(it + 1);               // vb dead; refill under MFMA phase

        // wave 0: finalize x2 for this tile while others head into MFMA
        if (w == 0) {
            const int t = it * 64 + l;
            float sum = x2p[0][l] + x2p[1][l] + x2p[2][l] + x2p[3][l]
                      + x2p[4][l] + x2p[5][l] + x2p[6][l] + x2p[7][l];
            x2f[l] = (t < T_DIM) ? sum : 1e30f;   // padded t never wins the min
        }

        f32x4 acc[4][4];
#pragma unroll
        for (int ps = 0; ps < 4; ++ps)
#pragma unroll
            for (int ts = 0; ts < 4; ++ts) acc[ps][ts] = (f32x4){0.f, 0.f, 0.f, 0.f};

        __builtin_amdgcn_s_setprio(1);
#pragma unroll
        for (int kst = 0; kst < 4; ++kst) {
            short8 bfr[4];
#pragma unroll
            for (int ts = 0; ts < 4; ++ts) {
                const int tl = ts * 16 + row16;
                const int gr = (kst * 4 + kq) ^ (tl & 7);
                bfr[ts] = *(const short8*)(smem + tl * 256 + (gr << 4));
            }
#pragma unroll
            for (int ps = 0; ps < 4; ++ps)
#pragma unroll
                for (int ts = 0; ts < 4; ++ts)
                    acc[ps][ts] = __builtin_amdgcn_mfma_f32_16x16x32_bf16(
                        afr[ps][kst], bfr[ts], acc[ps][ts], 0, 0, 0);
        }
        __builtin_amdgcn_s_setprio(0);

        __syncthreads();                       // bar B: x2f ready, tile dead

        float xv[4];
#pragma unroll
        for (int ts = 0; ts < 4; ++ts) xv[ts] = x2f[ts * 16 + row16];
#pragma unroll
        for (int ps = 0; ps < 4; ++ps)
#pragma unroll
            for (int ts = 0; ts < 4; ++ts)
#pragma unroll
                for (int q = 0; q < 4; ++q)
                    minv[ps][q] = fminf(minv[ps][q], fmaf(-2.f, acc[ps][ts][q], xv[ts]));

        if (more) {
            write_tile();                      // stage it+1
            __syncthreads();                   // bar A': next tile ready
        }
    }

    // min across the 16 t-columns (lane bits 0..3)
#pragma unroll
    for (int m = 1; m <= 8; m <<= 1)
#pragma unroll
        for (int ps = 0; ps < 4; ++ps)
#pragma unroll
            for (int q = 0; q < 4; ++q)
                minv[ps][q] = fminf(minv[ps][q], __shfl_xor(minv[ps][q], m));

    if (row16 == 0) {
#pragma unroll
        for (int ps = 0; ps < 4; ++ps) {
            const int p = wp + ps * 16 + kq * 4;   // C/D: row = kq*4+q
            *(float4*)(&wsmin[((size_t)th * B_DIM + b) * P_PAD + p]) =
                make_float4(minv[ps][0], minv[ps][1], minv[ps][2], minv[ps][3]);
        }
    }
}

// ---------------- combine: p2 + 2-way min-merge + clamp + log-sim + @W ----------------
__global__ __launch_bounds__(256) void combine_logits(
    const float* __restrict__ proto, const float* __restrict__ lw,
    const float* __restrict__ wsmin, float* __restrict__ out) {
    const int b = blockIdx.x, tid = threadIdx.x;
    float a[NCLS] = {0.f, 0.f, 0.f, 0.f, 0.f};
    for (int p = tid; p < P_DIM; p += 256) {
        const float4* pr = (const float4*)(proto + p * C_DIM);
        float p2 = 0.f;
#pragma unroll
        for (int i = 0; i < 32; ++i) {
            float4 u = pr[i];
            p2 += u.x*u.x + u.y*u.y + u.z*u.z + u.w*u.w;
        }
        const float m0 = wsmin[((size_t)0 * B_DIM + b) * P_PAD + p];
        const float m1 = wsmin[((size_t)1 * B_DIM + b) * P_PAD + p];
        const float m  = fminf(m0, m1);
        const float md = fmaxf(m + p2, 0.f);
        const float sim = logf((md + 1.f) / (md + EPSV));
#pragma unroll
        for (int n = 0; n < NCLS; ++n) a[n] = fmaf(sim, lw[p * NCLS + n], a[n]);
    }
#pragma unroll
    for (int m = 1; m <= 32; m <<= 1)
#pragma unroll
        for (int n = 0; n < NCLS; ++n) a[n] += __shfl_xor(a[n], m);
    __shared__ float red[4][NCLS];
    const int w = tid >> 6, l = tid & 63;
    if (l == 0) {
#pragma unroll
        for (int n = 0; n < NCLS; ++n) red[w][n] = a[n];
    }
    __syncthreads();
    if (tid < NCLS)
        out[b * NCLS + tid] = red[0][tid] + red[1][tid] + red[2][tid] + red[3][tid];
}

// ---------------- fallback (no workspace): slow but correct ----------------
__global__ __launch_bounds__(256) void fallback_k(const float* __restrict__ x,
                                                  const float* __restrict__ proto,
                                                  const float* __restrict__ lw,
                                                  float* __restrict__ out) {
    __shared__ float x2s[T_DIM];
    __shared__ float sims[P_DIM];
    int b = blockIdx.x, tid = threadIdx.x;
    for (int t = tid; t < T_DIM; t += 256) {
        float a = 0.f;
        for (int c = 0; c < C_DIM; ++c) { float v = x[((size_t)b * C_DIM + c) * T_DIM + t]; a = fmaf(v, v, a); }
        x2s[t] = a;
    }
    __syncthreads();
    for (int p = tid; p < P_DIM; p += 256) {
        float p2 = 0.f;
        for (int c = 0; c < C_DIM; ++c) { float v = proto[p * C_DIM + c]; p2 = fmaf(v, v, p2); }
        float mind = 1e30f;
        for (int t = 0; t < T_DIM; ++t) {
            float xp = 0.f;
            for (int c = 0; c < C_DIM; ++c)
                xp = fmaf(x[((size_t)b * C_DIM + c) * T_DIM + t], proto[p * C_DIM + c], xp);
            float d = fmaxf(x2s[t] - 2.f * xp + p2, 0.f);
            mind = fminf(mind, d);
        }
        sims[p] = logf((mind + 1.f) / (mind + EPSV));
    }
    __syncthreads();
    if (tid < NCLS) {
        float a = 0.f;
        for (int p = 0; p < P_DIM; ++p) a = fmaf(sims[p], lw[p * NCLS + tid], a);
        out[b * NCLS + tid] = a;
    }
}

extern "C" void kernel_launch(void* const* d_in, const int* in_sizes, int n_in,
                              void* d_out, int out_size, void* d_ws, size_t ws_size,
                              hipStream_t stream) {
    const float* x     = (const float*)d_in[0];
    const float* proto = (const float*)d_in[1];
    const float* lw    = (const float*)d_in[2];
    float* out = (float*)d_out;

    const size_t need = (size_t)2 * B_DIM * P_PAD * sizeof(float);   // 512 KB

    if (ws_size >= need) {
        float* wsmin = (float*)d_ws;
        fused_gemm_min<<<dim3(256), 512, 0, stream>>>(x, proto, wsmin);
        combine_logits<<<dim3(B_DIM), 256, 0, stream>>>(proto, lw, wsmin, out);
    } else {
        fallback_k<<<dim3(B_DIM), 256, 0, stream>>>(x, proto, lw, out);
    }
}